// Round 10
// baseline (369.825 us; speedup 1.0000x reference)
//
#include <hip/hip_runtime.h>
#include <stdint.h>

#define Bb 8
#define Cc 2048
#define Ee 1024

typedef unsigned short u16;
typedef __attribute__((ext_vector_type(8))) short short8;
typedef __attribute__((ext_vector_type(4))) float f32x4;

__device__ __forceinline__ u16 f2bf(float f){
    unsigned u = __builtin_bit_cast(unsigned, f);
    return (u16)((u + 0x7fffu + ((u >> 16) & 1u)) >> 16);   // RNE, finite inputs
}
__device__ __forceinline__ float bf2f(u16 h){
    return __builtin_bit_cast(float, ((unsigned)h) << 16);
}
__device__ __forceinline__ void gld16(const void* g, void* l){
    __builtin_amdgcn_global_load_lds(
        (const __attribute__((address_space(1))) unsigned int*)g,
        (__attribute__((address_space(3))) unsigned int*)l,
        16, 0, 0);
}
#define MFMA(a,b,c) __builtin_amdgcn_mfma_f32_16x16x32_bf16((a),(b),(c),0,0,0)
#define SBAR()  __builtin_amdgcn_s_barrier()
#define SCHED0() __builtin_amdgcn_sched_barrier(0)
#define LGKM4() asm volatile("s_waitcnt lgkmcnt(4)" ::: "memory")
#define LGKM0() asm volatile("s_waitcnt lgkmcnt(0)" ::: "memory")
#define VMCNT0() asm volatile("s_waitcnt vmcnt(0)" ::: "memory")

// ---------------- cast fp32 -> bf16 (vectorized) ----------------
__global__ __launch_bounds__(256) void k_cast(const float* __restrict__ s,
                                              u16* __restrict__ d, long n4){
    long i = (long)blockIdx.x * 256 + threadIdx.x;
    const long stride = (long)gridDim.x * 256;
    for (; i < n4; i += stride){
        float4 f = ((const float4*)s)[i];
        ushort4 o = make_ushort4(f2bf(f.x), f2bf(f.y), f2bf(f.z), f2bf(f.w));
        ((ushort4*)d)[i] = o;
    }
}

// ------ fused: x fp32 -> xb bf16 (straight) + xbT bf16 (transposed) ------
__global__ __launch_bounds__(256) void k_cast_xt(const float* __restrict__ src,
                                                 u16* __restrict__ xb,
                                                 u16* __restrict__ xbT){
    __shared__ float tile[32][33];
    const int b = blockIdx.z;
    src += (long)b * Cc * Ee;
    xb  += (long)b * Cc * Ee;
    xbT += (long)b * Cc * Ee;
    const int c0 = blockIdx.x * 32;   // E-dim block
    const int r0 = blockIdx.y * 32;   // C-dim block
    const int tx = threadIdx.x & 31;
    const int ty = threadIdx.x >> 5;  // 0..7
    #pragma unroll
    for (int p = 0; p < 4; ++p){
        float v = src[(long)(r0 + ty + p*8) * Ee + c0 + tx];
        tile[ty + p*8][tx] = v;
        xb[(long)(r0 + ty + p*8) * Ee + c0 + tx] = f2bf(v);
    }
    __syncthreads();
    #pragma unroll
    for (int p = 0; p < 4; ++p)
        xbT[(long)(c0 + ty + p*8) * Cc + r0 + tx] = f2bf(tile[tx][ty + p*8]);
}

// ====== 128x256 NT GEMM — per-wave 128x64 intensity + 2 blocks/CU decorrelation ======
// C[m,n] = scale*sum_k A[m,k]B[n,k] (+bias); A:[M,K], B:[N,K] bf16 row-major.
// 256 thr = 4 waves (1M x 4N), per-wave 128x64 (8m x 4n frags); BK=32.
// LDS 24KiB/buffer (A 8K + B 16K), double-buffered 48KiB -> 2 blocks/CU.
// Paired-row layout: LDS row (128B) = two 64B tile-rows {2r, 2r+1}; 16B chunk c
// stored at c ^ (ldsrow&7) -> ds_read_b128 is uniform 2-way bank aliasing (free).
// Staging keeps linear LDS dest (tid*16); inverse permutation folded into the
// per-thread GLOBAL source (row/chunk derived from tid).  [rule 21: both-sides]
// Per K-tile: 6 gld16 (t+1) up-front; reads b[0..3],a[0..7]; LGKM4 -> MFMA m0-3;
// LGKM0 -> MFMA m4-7; VMCNT0+SBAR.  2 resident blocks decorrelate the stalls.
template<int BIAS_MODE, int OUT_F32>
__global__ __launch_bounds__(256, 2)
void k_gemm_bn(const u16* __restrict__ A, const u16* __restrict__ Bm,
               void* __restrict__ Cout, const float* __restrict__ bias,
               int N, int K, long sA, long sB, long sC, float scale)
{
    __shared__ __attribute__((aligned(16))) char smem[49152];

    // ---- bijective XCD swizzle (nwg % 8 == 0 for all launches here)
    const int gx = gridDim.x, gy = gridDim.y;
    const int nwg = gx * gy * gridDim.z;
    const int lin = blockIdx.x + gx * (blockIdx.y + gy * blockIdx.z);
    const int swz = (lin & 7) * (nwg >> 3) + (lin >> 3);
    const int bx = swz % gx;
    const int tmp = swz / gx;
    const int by = tmp % gy;
    const int bz = tmp / gy;

    A  += (long)bz * sA;
    Bm += (long)bz * sB;
    u16*   Cm = (u16*)Cout + (OUT_F32 ? 0 : (long)bz * sC);
    float* Cf = (float*)Cout + (OUT_F32 ? (long)bz * sC : 0);

    const int tid  = threadIdx.x;
    const int lane = tid & 63;
    const int wc   = tid >> 6;         // wave 0..3 = N quarter
    const int tileM = bx * 128;
    const int tileN = by * 256;

    // ---- staging source mapping (paired-row + chunk-XOR, inverse on global side)
    // thread tid -> ldsrow_rel = tid>>3 (0..31), chunk c = tid&7;
    // logical chunk lc = c ^ (ldsrow_rel&7); tile row = ldsrow_rel*2 + (lc>>2);
    // k-chunk = lc&3.  Unit u covers 64 tile-rows (4KiB LDS).
    const int lr_  = tid >> 3;
    const int lc_  = (tid & 7) ^ (lr_ & 7);
    const int trow = lr_ * 2 + (lc_ >> 2);
    const int kch  = lc_ & 3;
    const u16* Agp = A  + (long)(tileM + trow) * K + kch * 8;
    const u16* Bgp = Bm + (long)(tileN + trow) * K + kch * 8;
    const long uK = (long)64 * K;                // global stride per unit
    const int  ldst = tid * 16;                  // linear LDS dest within unit

    // ---- ds_read constants: per-lane base offset (wave-uniform formula)
    // frag row r = (m*16 or wc*64+n*16) + lrow; addr = (r>>1)*128 + ((((r&1)<<2)|lk)^((r>>1)&7))*16
    // since m*8, wc*32, n*8 are ==0 mod 8, the XOR term depends only on lrow,lk:
    const int lrow = lane & 15;
    const int lk   = lane >> 4;                  // 0..3 (k chunk)
    const int roff = (lrow >> 1) * 128 + (((((lrow & 1) << 2) | lk) ^ ((lrow >> 1) & 7)) << 4);
    const int aoff = roff;                        // + m*1024
    const int boff = 8192 + wc * 4096 + roff;     // + n*1024

    f32x4 acc[8][4];
    #pragma unroll
    for (int m = 0; m < 8; ++m)
        #pragma unroll
        for (int n = 0; n < 4; ++n)
            acc[m][n] = (f32x4){0.f,0.f,0.f,0.f};

    char* sm = smem;
    // ---- prologue: stage tile 0 into buf0 (A: 2 units, B: 4 units), full drain
    #pragma unroll
    for (int u = 0; u < 2; ++u) gld16(Agp + u*uK, sm + u*4096 + ldst);
    #pragma unroll
    for (int u = 0; u < 4; ++u) gld16(Bgp + u*uK, sm + 8192 + u*4096 + ldst);
    __syncthreads();

    const int NT = K >> 5;                       // BK=32
    short8 aF[8], bF[4];

    for (int t = 0; t < NT; ++t){
        const bool pref = (t + 1) < NT;
        char* cbuf = sm + (t & 1) * 24576;
        char* nbuf = sm + ((t + 1) & 1) * 24576;
        const long g1 = (long)(t + 1) * 32;

        // ---- issue next tile's staging up-front (6 loads; land during compute)
        if (pref){
            gld16(Agp + g1 + 0*uK, nbuf + 0*4096 + ldst);
            gld16(Agp + g1 + 1*uK, nbuf + 1*4096 + ldst);
            gld16(Bgp + g1 + 0*uK, nbuf + 8192 + 0*4096 + ldst);
            gld16(Bgp + g1 + 1*uK, nbuf + 8192 + 1*4096 + ldst);
            gld16(Bgp + g1 + 2*uK, nbuf + 8192 + 2*4096 + ldst);
            gld16(Bgp + g1 + 3*4096/4096*uK*1, nbuf + 8192 + 3*4096 + ldst);
        }

        // ---- fragment reads: b first (4), then a (8)
        #pragma unroll
        for (int n = 0; n < 4; ++n) bF[n] = *(const short8*)(cbuf + boff + n*1024);
        #pragma unroll
        for (int m = 0; m < 8; ++m) aF[m] = *(const short8*)(cbuf + aoff + m*1024);

        LGKM4(); SCHED0();                       // b0-3 + a0-3 ready (a4-7 in flight)
        __builtin_amdgcn_s_setprio(1);
        #pragma unroll
        for (int m = 0; m < 4; ++m)
            #pragma unroll
            for (int n = 0; n < 4; ++n)
                acc[m][n] = MFMA(aF[m], bF[n], acc[m][n]);
        __builtin_amdgcn_s_setprio(0);

        LGKM0(); SCHED0();                       // a4-7 ready
        __builtin_amdgcn_s_setprio(1);
        #pragma unroll
        for (int m = 4; m < 8; ++m)
            #pragma unroll
            for (int n = 0; n < 4; ++n)
                acc[m][n] = MFMA(aF[m], bF[n], acc[m][n]);
        __builtin_amdgcn_s_setprio(0);

        // ---- tile boundary: own staging landed + all waves done reading cbuf
        VMCNT0(); SBAR(); SCHED0();
    }

    // ---- epilogue: C/D layout col=lane&15, row=(lane>>4)*4+j
    const int r0base = tileM + lk * 4;
    const int cbase  = tileN + wc * 64 + lrow;
    #pragma unroll
    for (int m = 0; m < 8; ++m){
        const int r0 = r0base + m * 16;
        #pragma unroll
        for (int n = 0; n < 4; ++n){
            const int c = cbase + n * 16;
            f32x4 v = acc[m][n];
            #pragma unroll
            for (int j = 0; j < 4; ++j){
                float val = v[j] * scale;
                if (BIAS_MODE == 1) val += bias[c];
                if (BIAS_MODE == 2) val += bias[r0 + j];
                if (OUT_F32) Cf[(long)(r0 + j) * N + c] = val;
                else         Cm[(long)(r0 + j) * N + c] = f2bf(val);
            }
        }
    }
}

// ---------------- row softmax, in-place on bf16 [rows x 2048] ----------------
__global__ __launch_bounds__(256) void k_softmax(u16* __restrict__ P){
    u16* p = P + (long)blockIdx.x * Cc;
    const int tid = threadIdx.x;
    short8 raw = *(const short8*)(p + tid * 8);
    float v[8];
    float mx = -3.0e38f;
    #pragma unroll
    for (int i = 0; i < 8; ++i){ v[i] = bf2f((u16)raw[i]); mx = fmaxf(mx, v[i]); }
    #pragma unroll
    for (int o = 32; o > 0; o >>= 1) mx = fmaxf(mx, __shfl_xor(mx, o));
    __shared__ float redm[4];
    if ((tid & 63) == 0) redm[tid >> 6] = mx;
    __syncthreads();
    mx = fmaxf(fmaxf(redm[0], redm[1]), fmaxf(redm[2], redm[3]));
    float s = 0.f;
    #pragma unroll
    for (int i = 0; i < 8; ++i){ v[i] = __expf(v[i] - mx); s += v[i]; }
    #pragma unroll
    for (int o = 32; o > 0; o >>= 1) s += __shfl_xor(s, o);
    __shared__ float reds[4];
    if ((tid & 63) == 0) reds[tid >> 6] = s;
    __syncthreads();
    s = reds[0] + reds[1] + reds[2] + reds[3];
    const float inv = 1.f / s;
    short8 o8;
    #pragma unroll
    for (int i = 0; i < 8; ++i) o8[i] = (short)f2bf(v[i] * inv);
    *(short8*)(p + tid * 8) = o8;
}

static inline int cast_grid(long n4){
    long g = (n4 + 255) / 256;
    return (int)(g > 2048 ? 2048 : g);
}

extern "C" void kernel_launch(void* const* d_in, const int* in_sizes, int n_in,
                              void* d_out, int out_size, void* d_ws, size_t ws_size,
                              hipStream_t stream)
{
    const float* x     = (const float*)d_in[0];
    const float* fc_w  = (const float*)d_in[1];
    const float* fc_b  = (const float*)d_in[2];
    const float* altw  = (const float*)d_in[3];
    const float* altb  = (const float*)d_in[4];
    const float* vfc_w = (const float*)d_in[5];
    const float* vfc_b = (const float*)d_in[6];
    float* out = (float*)d_out;   // reference output is fp32

    char* ws = (char*)d_ws;
    const size_t nBCE = (size_t)Bb * Cc * Ee;            // 16,777,216 elements
    u16* xb   = (u16*)(ws);                              // [B][C][E]
    u16* xbT  = (u16*)(ws + 2 * nBCE);                   // [B][E][C]
    u16* P    = (u16*)(ws);                              // [B][C][C] (aliases xb+xbT, dead by then)
    u16* y    = (u16*)(ws + 4 * nBCE);                   // [B][C][E]
    u16* z    = (u16*)(ws + 6 * nBCE);                   // [B][C][E]   z[b][k][e] = yx[b,e,k]
    u16* vxT  = (u16*)(ws + 8 * nBCE);                   // [B][E][C]   vxT[b][f][k] = vx[b,k,f]
    u16* fcwb = (u16*)(ws + 10 * nBCE);                  // [E][E]
    u16* vfwb = fcwb + (size_t)Ee * Ee;
    u16* awb  = vfwb + (size_t)Ee * Ee;                  // [C][C]

    // 1) casts (x: fused straight+transpose, single fp32 read)
    k_cast_xt<<<dim3(Ee / 32, Cc / 32, Bb), 256, 0, stream>>>(x, xb, xbT);
    k_cast<<<cast_grid((long)Ee * Ee / 4), 256, 0, stream>>>(fc_w, fcwb, (long)Ee * Ee / 4);
    k_cast<<<cast_grid((long)Ee * Ee / 4), 256, 0, stream>>>(vfc_w, vfwb, (long)Ee * Ee / 4);
    k_cast<<<cast_grid((long)Cc * Cc / 4), 256, 0, stream>>>(altw, awb, (long)Cc * Cc / 4);

    const long sBCE = (long)Cc * Ee;
    const long sBCC = (long)Cc * Cc;
    dim3 blk(256);

    // 2) y[b][c][f] = sum_e xb[c,e] fcw[f,e] + fc_b[f]        M=C,N=E,K=E
    k_gemm_bn<1, 0><<<dim3(Cc/128, Ee/256, Bb), blk, 0, stream>>>(
        xb, fcwb, y, fc_b, Ee, Ee, sBCE, 0, sBCE, 1.f);

    // 3) vxT[b][f][k] = sum_e vfcw[f,e] xb[k,e] + vfc_b[f]    M=E,N=C,K=E (bias per row)
    k_gemm_bn<2, 0><<<dim3(Ee/128, Cc/256, Bb), blk, 0, stream>>>(
        vfwb, xb, vxT, vfc_b, Cc, Ee, 0, sBCE, sBCE, 1.f);

    // 4) z[b][k][e] = sum_c altw[k,c] xT[e,c] + alt_b[k]      M=C,N=E,K=C (bias per row)
    k_gemm_bn<2, 0><<<dim3(Cc/128, Ee/256, Bb), blk, 0, stream>>>(
        awb, xbT, z, altb, Ee, Cc, 0, sBCE, sBCE, 1.f);

    // 5) P[b][c][k] = (1/sqrt(C)) * sum_e y[c,e] z[k,e]       M=C,N=C,K=E
    k_gemm_bn<0, 0><<<dim3(Cc/128, Cc/256, Bb), blk, 0, stream>>>(
        y, z, P, nullptr, Cc, Ee, sBCE, sBCE, sBCC, 0.022097086912079608f);

    // 6) softmax rows of P (in place)
    k_softmax<<<Bb * Cc, 256, 0, stream>>>(P);

    // 7) out[b][c][e] = sum_k P[c,k] vxT[e,k] -> fp32         M=C,N=E,K=C
    k_gemm_bn<0, 1><<<dim3(Cc/128, Ee/256, Bb), blk, 0, stream>>>(
        P, vxT, out, nullptr, Ee, Cc, sBCC, sBCE, sBCE, 1.f);
}

// Round 11
// 309.065 us; speedup vs baseline: 1.1966x; 1.1966x over previous
//
#include <hip/hip_runtime.h>
#include <stdint.h>

#define Bb 8
#define Cc 2048
#define Ee 1024

typedef unsigned short u16;
typedef __attribute__((ext_vector_type(8))) short short8;
typedef __attribute__((ext_vector_type(4))) float f32x4;

__device__ __forceinline__ u16 f2bf(float f){
    unsigned u = __builtin_bit_cast(unsigned, f);
    return (u16)((u + 0x7fffu + ((u >> 16) & 1u)) >> 16);   // RNE, finite inputs
}
__device__ __forceinline__ float bf2f(u16 h){
    return __builtin_bit_cast(float, ((unsigned)h) << 16);
}
__device__ __forceinline__ void gld16(const void* g, void* l){
    __builtin_amdgcn_global_load_lds(
        (const __attribute__((address_space(1))) unsigned int*)g,
        (__attribute__((address_space(3))) unsigned int*)l,
        16, 0, 0);
}
#define MFMA(a,b,c) __builtin_amdgcn_mfma_f32_16x16x32_bf16((a),(b),(c),0,0,0)
#define SBAR()  __builtin_amdgcn_s_barrier()
#define SCHED0() __builtin_amdgcn_sched_barrier(0)
#define LGKM8() asm volatile("s_waitcnt lgkmcnt(8)" ::: "memory")
#define LGKM4() asm volatile("s_waitcnt lgkmcnt(4)" ::: "memory")
#define LGKM0() asm volatile("s_waitcnt lgkmcnt(0)" ::: "memory")
#define VMCNT0() asm volatile("s_waitcnt vmcnt(0)" ::: "memory")

// ------ fused: x fp32 -> xb bf16 (straight) + xbT bf16 (transposed) ------
__global__ __launch_bounds__(256) void k_cast_xt(const float* __restrict__ src,
                                                 u16* __restrict__ xb,
                                                 u16* __restrict__ xbT){
    __shared__ float tile[32][33];
    const int b = blockIdx.z;
    src += (long)b * Cc * Ee;
    xb  += (long)b * Cc * Ee;
    xbT += (long)b * Cc * Ee;
    const int c0 = blockIdx.x * 32;   // E-dim block
    const int r0 = blockIdx.y * 32;   // C-dim block
    const int tx = threadIdx.x & 31;
    const int ty = threadIdx.x >> 5;  // 0..7
    #pragma unroll
    for (int p = 0; p < 4; ++p){
        float v = src[(long)(r0 + ty + p*8) * Ee + c0 + tx];
        tile[ty + p*8][tx] = v;
        xb[(long)(r0 + ty + p*8) * Ee + c0 + tx] = f2bf(v);
    }
    __syncthreads();
    #pragma unroll
    for (int p = 0; p < 4; ++p)
        xbT[(long)(c0 + ty + p*8) * Cc + r0 + tx] = f2bf(tile[tx][ty + p*8]);
}

// ------ merged cast of the 3 weight matrices (one launch) ------
__global__ __launch_bounds__(256) void k_cast3(const float* __restrict__ s0, u16* __restrict__ d0, long n0,
                                               const float* __restrict__ s1, u16* __restrict__ d1, long n1,
                                               const float* __restrict__ s2, u16* __restrict__ d2, long n2){
    long i = (long)blockIdx.x * 256 + threadIdx.x;
    const long stride = (long)gridDim.x * 256;
    const long tot = n0 + n1 + n2;
    for (; i < tot; i += stride){
        const float* s; u16* d; long k;
        if (i < n0)          { s = s0; d = d0; k = i; }
        else if (i < n0 + n1){ s = s1; d = d1; k = i - n0; }
        else                 { s = s2; d = d2; k = i - n0 - n1; }
        float4 f = ((const float4*)s)[k];
        ((ushort4*)d)[k] = make_ushort4(f2bf(f.x), f2bf(f.y), f2bf(f.z), f2bf(f.w));
    }
}

// ====== 256x256 NT GEMM — R8 core + fused softmax pieces + PRIO A/B ======
// C[m,n] = scale*sum_k A[m,k]B[n,k]; A:[M,K], B:[N,K] bf16 row-major.
// 512 thr = 8 waves (2M x 4N); BK=64; LDS 128KiB double-buffered.
// K-loop identical to R8 (best so far): 8 gld16 up-front, batched reads with
// counted lgkm, RAW-free cluster walk, one vmcnt(0)+barrier per tile.
// EPI: 0 = scale+bias store | 1 = store exp(s*scale) bf16 + per-row partial sums
//      (LDS cross-wave reduce -> extra[bz][row][by], no atomics)
//      | 2 = divide by rowsum (sum of 8 partials) -> fp32 store.
// PRIO: 1 = setprio(1) around MFMA clusters (R8 behavior), 0 = none (A/B probe).
template<int BIAS_MODE, int OUT_F32, int EPI, int PRIO>
__global__ __launch_bounds__(512, 2)
void k_gemm256(const u16* __restrict__ A, const u16* __restrict__ Bm,
               void* __restrict__ Cout, const float* __restrict__ bias,
               float* __restrict__ extra,
               int N, int K, long sA, long sB, long sC, float scale)
{
    __shared__ __attribute__((aligned(16))) char smem[131072];

    // ---- bijective XCD swizzle (nwg % 8 == 0 for all launches here)
    const int gx = gridDim.x, gy = gridDim.y;
    const int nwg = gx * gy * gridDim.z;
    const int lin = blockIdx.x + gx * (blockIdx.y + gy * blockIdx.z);
    const int swz = (lin & 7) * (nwg >> 3) + (lin >> 3);
    const int bx = swz % gx;
    const int tmp = swz / gx;
    const int by = tmp % gy;
    const int bz = tmp / gy;

    A  += (long)bz * sA;
    Bm += (long)bz * sB;
    u16*   Cm = (u16*)Cout + (OUT_F32 ? 0 : (long)bz * sC);
    float* Cf = (float*)Cout + (OUT_F32 ? (long)bz * sC : 0);

    const int tid  = threadIdx.x;
    const int lane = tid & 63;
    const int wave = tid >> 6;
    const int wr = wave >> 2;          // 0..1  (M half)
    const int wc = wave & 3;           // 0..3  (N quarter)
    const int tileM = bx * 256;
    const int tileN = by * 256;

    // ---- staging constants: unit = 64 rows x 64 cols (8KiB) = 1 gld16/thread
    const int srow   = tid >> 3;                 // 0..63 (row within unit)
    const int schunk = (tid & 7) ^ (srow & 7);   // pre-swizzled 16B chunk
    const u16* Ag = A  + (long)(tileM + srow) * K + schunk * 8;
    const u16* Bg = Bm + (long)(tileN + srow) * K + schunk * 8;
    const long uK = (long)64 * K;                // global stride per unit
    const int  ldst = tid * 16;                  // linear LDS dest

    // ---- ds_read constants (swizzled chunk)
    const int lrow = lane & 15;
    const int lk   = lane >> 4;                  // 0..3
    const int sw   = lrow & 7;
    const int cs0  = ((0 + lk) ^ sw) * 16;       // kk=0 chunk byte
    const int cs1  = ((4 + lk) ^ sw) * 16;       // kk=1 chunk byte
    const int arow0 = (wr*128 + lrow) * 128;             // A row byte off in tile
    const int brow0 = 32768 + (wc*64 + lrow) * 128;      // B row byte off in tile

    f32x4 acc[8][4];
    #pragma unroll
    for (int m = 0; m < 8; ++m)
        #pragma unroll
        for (int n = 0; n < 4; ++n)
            acc[m][n] = (f32x4){0.f,0.f,0.f,0.f};

    char* sm = smem;
    // ---- prologue: stage tile 0 into buf0, full drain (one-time)
    #pragma unroll
    for (int u = 0; u < 4; ++u) gld16(Bg + u*uK, sm + 32768 + u*8192 + ldst);
    #pragma unroll
    for (int u = 0; u < 4; ++u) gld16(Ag + u*uK, sm + u*8192 + ldst);
    __syncthreads();

    const int NT = K >> 6;
    short8 aE[4], aO[4], bE[4], bO[4];

    for (int t = 0; t < NT; ++t){
        const bool pref = (t + 1) < NT;
        char* cbuf = sm + ((t & 1) << 16);
        char* nbuf = sm + (((t + 1) & 1) << 16);
        const u16* Agt = Ag + (long)(t + 1) * 64;
        const u16* Bgt = Bg + (long)(t + 1) * 64;

        if (pref){
            gld16(Agt + 0*uK, nbuf + 0*8192 + ldst);
            gld16(Agt + 1*uK, nbuf + 1*8192 + ldst);
            gld16(Agt + 2*uK, nbuf + 2*8192 + ldst);
            gld16(Agt + 3*uK, nbuf + 3*8192 + ldst);
            gld16(Bgt + 0*uK, nbuf + 32768 + 0*8192 + ldst);
            gld16(Bgt + 1*uK, nbuf + 32768 + 1*8192 + ldst);
            gld16(Bgt + 2*uK, nbuf + 32768 + 2*8192 + ldst);
            gld16(Bgt + 3*uK, nbuf + 32768 + 3*8192 + ldst);
        }

        // ---- batch1: aE(m0-3,kk0), bE(kk0), aO(m4-7,kk0)  [12 reads]
        #pragma unroll
        for (int m = 0; m < 4; ++m) aE[m] = *(const short8*)(cbuf + arow0 + m*2048 + cs0);
        #pragma unroll
        for (int n = 0; n < 4; ++n) bE[n] = *(const short8*)(cbuf + brow0 + n*2048 + cs0);
        #pragma unroll
        for (int m = 0; m < 4; ++m) aO[m] = *(const short8*)(cbuf + arow0 + (m+4)*2048 + cs0);

        LGKM4(); SCHED0();
        if (PRIO) __builtin_amdgcn_s_setprio(1);
        #pragma unroll
        for (int m = 0; m < 4; ++m)              // q0: acc[0-3]
            #pragma unroll
            for (int n = 0; n < 4; ++n)
                acc[m][n] = MFMA(aE[m], bE[n], acc[m][n]);
        if (PRIO) __builtin_amdgcn_s_setprio(0);

        // ---- batch2: aE <- (m0-3,kk1), bO(kk1)  [8 reads]
        #pragma unroll
        for (int m = 0; m < 4; ++m) aE[m] = *(const short8*)(cbuf + arow0 + m*2048 + cs1);
        #pragma unroll
        for (int n = 0; n < 4; ++n) bO[n] = *(const short8*)(cbuf + brow0 + n*2048 + cs1);
        LGKM8(); SCHED0();
        if (PRIO) __builtin_amdgcn_s_setprio(1);
        #pragma unroll
        for (int m = 0; m < 4; ++m)              // q1: acc[4-7]
            #pragma unroll
            for (int n = 0; n < 4; ++n)
                acc[m+4][n] = MFMA(aO[m], bE[n], acc[m+4][n]);
        if (PRIO) __builtin_amdgcn_s_setprio(0);

        // ---- batch3: aO <- (m4-7,kk1)  [4 reads]
        #pragma unroll
        for (int m = 0; m < 4; ++m) aO[m] = *(const short8*)(cbuf + arow0 + (m+4)*2048 + cs1);
        LGKM4(); SCHED0();
        if (PRIO) __builtin_amdgcn_s_setprio(1);
        #pragma unroll
        for (int m = 0; m < 4; ++m)              // q2: acc[0-3]
            #pragma unroll
            for (int n = 0; n < 4; ++n)
                acc[m][n] = MFMA(aE[m], bO[n], acc[m][n]);
        if (PRIO) __builtin_amdgcn_s_setprio(0);

        LGKM0(); SCHED0();
        if (PRIO) __builtin_amdgcn_s_setprio(1);
        #pragma unroll
        for (int m = 0; m < 4; ++m)              // q3: acc[4-7]
            #pragma unroll
            for (int n = 0; n < 4; ++n)
                acc[m+4][n] = MFMA(aO[m], bO[n], acc[m+4][n]);
        if (PRIO) __builtin_amdgcn_s_setprio(0);

        VMCNT0(); SBAR(); SCHED0();
    }

    // ---- epilogue: C/D layout col=lane&15, row=(lane>>4)*4+j
    const int r0base = tileM + wr*128 + lk*4;
    const int cbase  = tileN + wc*64 + lrow;

    if (EPI == 0){
        #pragma unroll
        for (int m = 0; m < 8; ++m){
            const int r0 = r0base + m*16;
            #pragma unroll
            for (int n = 0; n < 4; ++n){
                const int c = cbase + n*16;
                f32x4 v = acc[m][n];
                #pragma unroll
                for (int j = 0; j < 4; ++j){
                    float val = v[j] * scale;
                    if (BIAS_MODE == 1) val += bias[c];
                    if (BIAS_MODE == 2) val += bias[r0 + j];
                    if (OUT_F32) Cf[(long)(r0 + j) * N + c] = val;
                    else         Cm[(long)(r0 + j) * N + c] = f2bf(val);
                }
            }
        }
    } else if (EPI == 1){
        // store exp(s*scale) bf16; per-row partial sums -> extra[bz][row][by]
        float* lsum = (float*)smem;              // [256 rows][4 wc] fp32 (4KB)
        const int rl0 = wr*128 + lk*4;           // local row base
        #pragma unroll
        for (int m = 0; m < 8; ++m){
            const int r0 = r0base + m*16;
            #pragma unroll
            for (int j = 0; j < 4; ++j){
                float rp = 0.f;
                #pragma unroll
                for (int n = 0; n < 4; ++n){
                    float e = __expf(acc[m][n][j] * scale);
                    rp += e;
                    Cm[(long)(r0 + j) * N + (cbase + n*16)] = f2bf(e);
                }
                rp += __shfl_xor(rp, 1);
                rp += __shfl_xor(rp, 2);
                rp += __shfl_xor(rp, 4);
                rp += __shfl_xor(rp, 8);
                if (lrow == 0)
                    lsum[(rl0 + m*16 + j)*4 + wc] = rp;
            }
        }
        __syncthreads();
        if (tid < 256){
            float4 v4 = ((const float4*)lsum)[tid];
            extra[((long)bz*Cc + tileM + tid)*8 + by] = v4.x + v4.y + v4.z + v4.w;
        }
    } else {  // EPI == 2: divide by row sum (8 partials), fp32 out
        #pragma unroll
        for (int m = 0; m < 8; ++m){
            const int r0 = r0base + m*16;
            #pragma unroll
            for (int j = 0; j < 4; ++j){
                const float4* pr = (const float4*)(extra + ((long)bz*Cc + r0 + j)*8);
                float4 pa = pr[0], pb = pr[1];
                float S = pa.x+pa.y+pa.z+pa.w + pb.x+pb.y+pb.z+pb.w;
                const float inv = 1.f / S;
                #pragma unroll
                for (int n = 0; n < 4; ++n)
                    Cf[(long)(r0 + j) * N + (cbase + n*16)] = acc[m][n][j] * inv;
            }
        }
    }
}

extern "C" void kernel_launch(void* const* d_in, const int* in_sizes, int n_in,
                              void* d_out, int out_size, void* d_ws, size_t ws_size,
                              hipStream_t stream)
{
    const float* x     = (const float*)d_in[0];
    const float* fc_w  = (const float*)d_in[1];
    const float* fc_b  = (const float*)d_in[2];
    const float* altw  = (const float*)d_in[3];
    const float* altb  = (const float*)d_in[4];
    const float* vfc_w = (const float*)d_in[5];
    const float* vfc_b = (const float*)d_in[6];
    float* out = (float*)d_out;   // reference output is fp32

    char* ws = (char*)d_ws;
    const size_t nBCE = (size_t)Bb * Cc * Ee;            // 16,777,216 elements
    u16* xb   = (u16*)(ws);                              // [B][C][E]
    u16* xbT  = (u16*)(ws + 2 * nBCE);                   // [B][E][C]
    u16* P    = (u16*)(ws);                              // [B][C][C] (aliases xb+xbT, dead by then)
    u16* y    = (u16*)(ws + 4 * nBCE);                   // [B][C][E]
    u16* z    = (u16*)(ws + 6 * nBCE);                   // [B][C][E]   z[b][k][e] = yx[b,e,k]
    u16* vxT  = (u16*)(ws + 8 * nBCE);                   // [B][E][C]   vxT[b][f][k] = vx[b,k,f]
    u16* fcwb = (u16*)(ws + 10 * nBCE);                  // [E][E]
    u16* vfwb = fcwb + (size_t)Ee * Ee;
    u16* awb  = vfwb + (size_t)Ee * Ee;                  // [C][C]
    // row-sum partials [B][C][8] fp32 (512KB) — reuses fcwb region (dead after y-GEMM)
    float* rpart = (float*)(ws + 10 * nBCE);

    // 1) casts
    k_cast_xt<<<dim3(Ee / 32, Cc / 32, Bb), 256, 0, stream>>>(x, xb, xbT);
    k_cast3<<<2048, 256, 0, stream>>>(fc_w, fcwb, (long)Ee * Ee / 4,
                                      vfc_w, vfwb, (long)Ee * Ee / 4,
                                      altw, awb, (long)Cc * Cc / 4);

    const long sBCE = (long)Cc * Ee;
    const long sBCC = (long)Cc * Cc;
    dim3 blk(512);

    // 2) y[b][c][f] = sum_e xb[c,e] fcw[f,e] + fc_b[f]        M=C,N=E,K=E   [PRIO=1]
    k_gemm256<1, 0, 0, 1><<<dim3(Cc/256, Ee/256, Bb), blk, 0, stream>>>(
        xb, fcwb, y, fc_b, nullptr, Ee, Ee, sBCE, 0, sBCE, 1.f);

    // 3) vxT[b][f][k] = sum_e vfcw[f,e] xb[k,e] + vfc_b[f]    M=E,N=C,K=E   [PRIO=1]
    k_gemm256<2, 0, 0, 1><<<dim3(Ee/256, Cc/256, Bb), blk, 0, stream>>>(
        vfwb, xb, vxT, vfc_b, nullptr, Cc, Ee, 0, sBCE, sBCE, 1.f);

    // 4) z[b][k][e] = sum_c altw[k,c] xT[e,c] + alt_b[k]      M=C,N=E,K=C   [PRIO=0 A/B]
    k_gemm256<2, 0, 0, 0><<<dim3(Cc/256, Ee/256, Bb), blk, 0, stream>>>(
        awb, xbT, z, altb, nullptr, Ee, Cc, 0, sBCE, sBCE, 1.f);

    // 5) Pexp[b][c][k] = exp(scale * sum_e y[c,e] z[k,e]); row partials -> rpart
    //    M=C,N=C,K=E   [PRIO=1, EPI=1]
    k_gemm256<0, 0, 1, 1><<<dim3(Cc/256, Cc/256, Bb), blk, 0, stream>>>(
        y, z, P, nullptr, rpart, Cc, Ee, sBCE, sBCE, sBCC, 0.022097086912079608f);

    // 6) out[b][c][e] = (sum_k Pexp[c,k] vxT[e,k]) / rowsum[c] -> fp32
    //    M=C,N=E,K=C   [PRIO=0 A/B, EPI=2]
    k_gemm256<0, 1, 2, 0><<<dim3(Cc/256, Ee/256, Bb), blk, 0, stream>>>(
        P, vxT, out, nullptr, rpart, Ee, Cc, sBCC, sBCE, sBCE, 1.f);
}